// Round 4
// baseline (679.209 us; speedup 1.0000x reference)
//
#include <hip/hip_runtime.h>
#include <hip/hip_fp16.h>

typedef unsigned short ushort_t;
typedef short bf16x8 __attribute__((ext_vector_type(8)));
typedef float f32x4 __attribute__((ext_vector_type(4)));
typedef _Float16 h2v __attribute__((ext_vector_type(2)));

#define B_SZ 32
#define T_SZ 256
#define V_SZ 10000
#define E_DIM 300
#define M_DIM 128
#define H_SZ 256

__device__ __forceinline__ ushort_t f2bf(float f) {
  unsigned u = __float_as_uint(f);
  unsigned r = u + 0x7fffu + ((u >> 16) & 1u);
  return (ushort_t)(r >> 16);
}

// ---------------- elementwise cast f32 -> bf16 ----------------
__global__ void k_cast_bf16(const float* __restrict__ in, ushort_t* __restrict__ out, int n) {
  int i = blockIdx.x * blockDim.x + threadIdx.x;
  if (i < n) out[i] = f2bf(in[i]);
}

// ---------------- transpose + cast: out[c][r] = in[r][c], zero-padded ----------------
// MODE 0: bf16 output, MODE 1: f16 output. out dims [Cp][Rp].
template <int MODE>
__global__ void k_transpose_cast(const float* __restrict__ in, ushort_t* __restrict__ out,
                                 int R, int C, int Rp, int Cp) {
  __shared__ float tile[32][33];
  int c0 = blockIdx.x * 32, r0 = blockIdx.y * 32;
  int tx = threadIdx.x, ty = threadIdx.y;  // (32,8)
#pragma unroll
  for (int i = 0; i < 32; i += 8) {
    int r = r0 + ty + i, c = c0 + tx;
    tile[ty + i][tx] = (r < R && c < C) ? in[(size_t)r * C + c] : 0.f;
  }
  __syncthreads();
#pragma unroll
  for (int i = 0; i < 32; i += 8) {
    int c = c0 + ty + i, r = r0 + tx;
    if (c < Cp && r < Rp) {
      float v = tile[tx][ty + i];
      if (MODE == 0) {
        out[(size_t)c * Rp + r] = f2bf(v);
      } else {
        __half h = __float2half(v);
        out[(size_t)c * Rp + r] = *(ushort_t*)&h;
      }
    }
  }
}

// ---------------- fuse: x_b[m][kp] = bf16(xtmp[m][kp] + E[words[m]][kp]) (kp<300), else 0 ----
__global__ void k_xfuse(const float* __restrict__ xtmp, const float* __restrict__ E,
                        const int* __restrict__ words, ushort_t* __restrict__ xb) {
  int m = blockIdx.x;
  int kp = threadIdx.x;  // 320 threads
  int w = words[m];
  float v = 0.f;
  if (kp < E_DIM) v = xtmp[(size_t)m * 320 + kp] + E[(size_t)w * E_DIM + kp];
  xb[(size_t)m * 320 + kp] = f2bf(v);
}

// ---------------- bf16 MFMA GEMM: C[m][n] = sum_k A[m][k]*BT[n][k] + bias[n] ----------------
// A: [M][K] bf16 row-major. BT: [Npad][K] bf16 row-major (pre-transposed B).
// 128x128 tile per block, 4 waves (2x2 of 64x64), BK=64, XOR-swizzled LDS.
__global__ __launch_bounds__(256, 2) void k_gemm_bt(
    const ushort_t* __restrict__ A, const ushort_t* __restrict__ BT,
    const float* __restrict__ bias, float* __restrict__ C,
    int M, int K, int Nreal, int ldc) {
  __shared__ __align__(16) char smem[32768];
  char* As = smem;            // [128 rows][8 slots of 16B], slot = c16 ^ (row&7)
  char* Bs = smem + 16384;
  const int tid = threadIdx.x;
  const int lane = tid & 63;
  const int w = tid >> 6;
  const int wr = w >> 1, wc = w & 1;
  const int m0 = blockIdx.x * 128;   // m-tile fastest-varying: same-B-panel blocks adjacent
  const int n0 = blockIdx.y * 128;

  f32x4 acc[4][4];
#pragma unroll
  for (int i = 0; i < 4; ++i)
#pragma unroll
    for (int j = 0; j < 4; ++j) acc[i][j] = (f32x4){0.f, 0.f, 0.f, 0.f};

  const int srow = tid >> 3;   // 0..31
  const int sc16 = tid & 7;    // 0..7

  for (int k0 = 0; k0 < K; k0 += 64) {
    __syncthreads();
#pragma unroll
    for (int it = 0; it < 4; ++it) {
      int row = srow + it * 32;
      int slot = sc16 ^ (row & 7);
      bf16x8 va = *(const bf16x8*)(A + (size_t)(m0 + row) * K + k0 + sc16 * 8);
      *(bf16x8*)(As + row * 128 + (slot << 4)) = va;
      bf16x8 vb = *(const bf16x8*)(BT + (size_t)(n0 + row) * K + k0 + sc16 * 8);
      *(bf16x8*)(Bs + row * 128 + (slot << 4)) = vb;
    }
    __syncthreads();

    bf16x8 af[4][2], bfr[4][2];
#pragma unroll
    for (int mi = 0; mi < 4; ++mi) {
      int r = wr * 64 + mi * 16 + (lane & 15);
#pragma unroll
      for (int kk = 0; kk < 2; ++kk) {
        int c16 = kk * 4 + (lane >> 4);
        af[mi][kk] = *(const bf16x8*)(As + r * 128 + ((c16 ^ (r & 7)) << 4));
      }
    }
#pragma unroll
    for (int ni = 0; ni < 4; ++ni) {
      int r = wc * 64 + ni * 16 + (lane & 15);
#pragma unroll
      for (int kk = 0; kk < 2; ++kk) {
        int c16 = kk * 4 + (lane >> 4);
        bfr[ni][kk] = *(const bf16x8*)(Bs + r * 128 + ((c16 ^ (r & 7)) << 4));
      }
    }
#pragma unroll
    for (int mi = 0; mi < 4; ++mi)
#pragma unroll
      for (int ni = 0; ni < 4; ++ni)
#pragma unroll
        for (int kk = 0; kk < 2; ++kk)
          acc[mi][ni] = __builtin_amdgcn_mfma_f32_16x16x32_bf16(af[mi][kk], bfr[ni][kk],
                                                                acc[mi][ni], 0, 0, 0);
  }

  // epilogue: D row=(lane>>4)*4+reg, col=lane&15  [verified m89 layout]
  const int rbase = m0 + wr * 64 + (lane >> 4) * 4;
  const int cbase = n0 + wc * 64 + (lane & 15);
#pragma unroll
  for (int ni = 0; ni < 4; ++ni) {
    int n = cbase + ni * 16;
    if (n < Nreal) {
      float bn = bias[n];
#pragma unroll
      for (int mi = 0; mi < 4; ++mi) {
#pragma unroll
        for (int rg = 0; rg < 4; ++rg) {
          int mrow = rbase + mi * 16 + rg;
          C[(size_t)mrow * ldc + n] = acc[mi][ni][rg] + bn;
        }
      }
    }
  }
}

// ---------------- GRU: 256 threads, thread j owns ALL THREE gate columns ----------------
// U columns j, j+256, j+512 register-resident as f16 (384 VGPRs). Per step: 32 broadcast
// ds_read_b128 of h feed 12 fdot2 each. Gates fully thread-local; 1 barrier/step
// (double-buffered h). 32 blocks (1/batch), 4 waves, 1 wave/SIMD.
__global__ __launch_bounds__(256) void k_gru(
    const float* __restrict__ gx, const ushort_t* __restrict__ UT,
    const float* __restrict__ bu, const int* __restrict__ words,
    ushort_t* __restrict__ seqb) {
  const int b = blockIdx.x;
  const int j = threadIdx.x;  // 0..255
  __shared__ __align__(16) _Float16 hbuf[2][H_SZ];
  __shared__ int words_s[T_SZ];

  // register-resident U columns (f16): z, r, n
  h2v uz[128], ur[128], un[128];
  {
    const h2v* pz = (const h2v*)(UT + (size_t)j * H_SZ);
    const h2v* pr = (const h2v*)(UT + (size_t)(H_SZ + j) * H_SZ);
    const h2v* pn = (const h2v*)(UT + (size_t)(2 * H_SZ + j) * H_SZ);
#pragma unroll
    for (int k = 0; k < 128; ++k) uz[k] = pz[k];
#pragma unroll
    for (int k = 0; k < 128; ++k) ur[k] = pr[k];
#pragma unroll
    for (int k = 0; k < 128; ++k) un[k] = pn[k];
  }
  const float buz = bu[j];
  const float bur = bu[H_SZ + j];
  const float bun = bu[2 * H_SZ + j];

  hbuf[0][j] = (_Float16)0.f;
  words_s[j] = words[b * T_SZ + j];
  __syncthreads();

  const float* gxp = gx + (size_t)b * T_SZ * 768;
  float gxz = gxp[j];
  float gxr = gxp[H_SZ + j];
  float gxn = gxp[2 * H_SZ + j];
  float h_old = 0.f;
  int p = 0;

  for (int t = 0; t < T_SZ; ++t) {
    // prefetch next step's gx under the dot-product phase
    float gxz_n = 0.f, gxr_n = 0.f, gxn_n = 0.f;
    if (t + 1 < T_SZ) {
      const float* g1 = gxp + (size_t)(t + 1) * 768;
      gxz_n = g1[j];
      gxr_n = g1[H_SZ + j];
      gxn_n = g1[2 * H_SZ + j];
    }

    const float4* hb4 = (const float4*)hbuf[p];
    float az0 = 0.f, az1 = 0.f, az2 = 0.f, az3 = 0.f;
    float ar0 = 0.f, ar1 = 0.f, ar2 = 0.f, ar3 = 0.f;
    float an0 = 0.f, an1 = 0.f, an2 = 0.f, an3 = 0.f;
#pragma unroll
    for (int k4 = 0; k4 < 32; ++k4) {
      float4 hv = hb4[k4];  // broadcast read: 8 h values (f16)
      const h2v* hp = (const h2v*)(&hv);
      az0 = __builtin_amdgcn_fdot2(uz[4 * k4 + 0], hp[0], az0, false);
      ar0 = __builtin_amdgcn_fdot2(ur[4 * k4 + 0], hp[0], ar0, false);
      an0 = __builtin_amdgcn_fdot2(un[4 * k4 + 0], hp[0], an0, false);
      az1 = __builtin_amdgcn_fdot2(uz[4 * k4 + 1], hp[1], az1, false);
      ar1 = __builtin_amdgcn_fdot2(ur[4 * k4 + 1], hp[1], ar1, false);
      an1 = __builtin_amdgcn_fdot2(un[4 * k4 + 1], hp[1], an1, false);
      az2 = __builtin_amdgcn_fdot2(uz[4 * k4 + 2], hp[2], az2, false);
      ar2 = __builtin_amdgcn_fdot2(ur[4 * k4 + 2], hp[2], ar2, false);
      an2 = __builtin_amdgcn_fdot2(un[4 * k4 + 2], hp[2], an2, false);
      az3 = __builtin_amdgcn_fdot2(uz[4 * k4 + 3], hp[3], az3, false);
      ar3 = __builtin_amdgcn_fdot2(ur[4 * k4 + 3], hp[3], ar3, false);
      an3 = __builtin_amdgcn_fdot2(un[4 * k4 + 3], hp[3], an3, false);
    }
    float hz = (az0 + az1) + (az2 + az3) + buz;
    float hr = (ar0 + ar1) + (ar2 + ar3) + bur;
    float hn = (an0 + an1) + (an2 + an3) + bun;

    float z = 1.f / (1.f + __expf(-(gxz + hz)));
    float r = 1.f / (1.f + __expf(-(gxr + hr)));
    float nv = 2.f / (1.f + __expf(-2.f * (gxn + r * hn))) - 1.f;  // tanh
    float hnew = (words_s[t] != 0) ? (z * h_old + (1.f - z) * nv) : h_old;
    h_old = hnew;
    seqb[((size_t)b * T_SZ + t) * H_SZ + j] = f2bf(hnew);
    hbuf[p ^ 1][j] = (_Float16)hnew;
    __syncthreads();

    gxz = gxz_n;
    gxr = gxr_n;
    gxn = gxn_n;
    p ^= 1;
  }
}

// ---------------- launcher ----------------
extern "C" void kernel_launch(void* const* d_in, const int* in_sizes, int n_in,
                              void* d_out, int out_size, void* d_ws, size_t ws_size,
                              hipStream_t stream) {
  const int*   words = (const int*)d_in[0];    // [32,256]
  const float* midis = (const float*)d_in[1];  // [32,256,128]
  const float* E     = (const float*)d_in[2];  // [10000,300]
  const float* Wm    = (const float*)d_in[3];  // [128,300]
  const float* bm    = (const float*)d_in[4];  // [300]
  const float* Wx    = (const float*)d_in[5];  // [300,768]
  const float* bx    = (const float*)d_in[6];  // [768]
  const float* U     = (const float*)d_in[7];  // [256,768]
  const float* bu    = (const float*)d_in[8];  // [768]
  const float* Wo    = (const float*)d_in[9];  // [256,10000]
  const float* bo    = (const float*)d_in[10]; // [10000]
  float* out = (float*)d_out;

  const int MT = B_SZ * T_SZ;  // 8192
  size_t off = 0;
  auto alloc = [&](size_t bytes) -> void* {
    void* p = (char*)d_ws + off;
    off += (bytes + 255) & ~(size_t)255;
    return p;
  };
  ushort_t* mid_b = (ushort_t*)alloc((size_t)MT * 128 * 2);
  ushort_t* WmT   = (ushort_t*)alloc((size_t)384 * 128 * 2);
  float*    xtmp  = (float*)   alloc((size_t)MT * 320 * 4);
  ushort_t* x_b   = (ushort_t*)alloc((size_t)MT * 320 * 2);
  ushort_t* WxT   = (ushort_t*)alloc((size_t)768 * 320 * 2);
  float*    gx    = (float*)   alloc((size_t)MT * 768 * 4);
  ushort_t* UT    = (ushort_t*)alloc((size_t)768 * 256 * 2);
  ushort_t* seq_b = (ushort_t*)alloc((size_t)MT * 256 * 2);
  ushort_t* WoT   = (ushort_t*)alloc((size_t)10112 * 256 * 2);
  (void)ws_size;

  // prep: casts + transposes
  k_cast_bf16<<<(MT * 128 + 255) / 256, 256, 0, stream>>>(midis, mid_b, MT * 128);
  k_transpose_cast<0><<<dim3(12, 4),  dim3(32, 8), 0, stream>>>(Wm, WmT, 128, 300, 128, 384);
  k_transpose_cast<0><<<dim3(24, 10), dim3(32, 8), 0, stream>>>(Wx, WxT, 300, 768, 320, 768);
  k_transpose_cast<0><<<dim3(316, 8), dim3(32, 8), 0, stream>>>(Wo, WoT, 256, 10000, 256, 10112);
  k_transpose_cast<1><<<dim3(24, 8),  dim3(32, 8), 0, stream>>>(U, UT, 256, 768, 256, 768);

  // xtmp = midis @ Wm + bm   (M=8192, K=128, Npad=384, Nreal=300, ldc=320)
  k_gemm_bt<<<dim3(64, 3), 256, 0, stream>>>(mid_b, WmT, bm, xtmp, MT, 128, 300, 320);
  // x_b = bf16(xtmp + E[words]) with k-pad zeros
  k_xfuse<<<MT, 320, 0, stream>>>(xtmp, E, words, x_b);
  // gx = x @ Wx + bx   (K=320, N=768)
  k_gemm_bt<<<dim3(64, 6), 256, 0, stream>>>(x_b, WxT, bx, gx, MT, 320, 768, 768);
  // GRU -> seq_b (bf16), register-resident-U VALU version
  k_gru<<<B_SZ, 256, 0, stream>>>(gx, UT, bu, words, seq_b);
  // logits = seq @ Wo + bo   (K=256, Npad=10112, Nreal=10000)
  k_gemm_bt<<<dim3(64, 79), 256, 0, stream>>>(seq_b, WoT, bo, out, MT, 256, 10000, 10000);
}

// Round 5
// 493.381 us; speedup vs baseline: 1.3766x; 1.3766x over previous
//
#include <hip/hip_runtime.h>
#include <hip/hip_fp16.h>

typedef unsigned short ushort_t;
typedef short bf16x8 __attribute__((ext_vector_type(8)));
typedef float f32x4 __attribute__((ext_vector_type(4)));
typedef _Float16 h2v __attribute__((ext_vector_type(2)));

#define B_SZ 32
#define T_SZ 256
#define V_SZ 10000
#define E_DIM 300
#define M_DIM 128
#define H_SZ 256

__device__ __forceinline__ ushort_t f2bf(float f) {
  unsigned u = __float_as_uint(f);
  unsigned r = u + 0x7fffu + ((u >> 16) & 1u);
  return (ushort_t)(r >> 16);
}

// ---------------- elementwise cast f32 -> bf16 ----------------
__global__ void k_cast_bf16(const float* __restrict__ in, ushort_t* __restrict__ out, int n) {
  int i = blockIdx.x * blockDim.x + threadIdx.x;
  if (i < n) out[i] = f2bf(in[i]);
}

// ---------------- transpose + cast: out[c][r] = in[r][c], zero-padded ----------------
// MODE 0: bf16 output, MODE 1: f16 output. out dims [Cp][Rp].
template <int MODE>
__global__ void k_transpose_cast(const float* __restrict__ in, ushort_t* __restrict__ out,
                                 int R, int C, int Rp, int Cp) {
  __shared__ float tile[32][33];
  int c0 = blockIdx.x * 32, r0 = blockIdx.y * 32;
  int tx = threadIdx.x, ty = threadIdx.y;  // (32,8)
#pragma unroll
  for (int i = 0; i < 32; i += 8) {
    int r = r0 + ty + i, c = c0 + tx;
    tile[ty + i][tx] = (r < R && c < C) ? in[(size_t)r * C + c] : 0.f;
  }
  __syncthreads();
#pragma unroll
  for (int i = 0; i < 32; i += 8) {
    int c = c0 + ty + i, r = r0 + tx;
    if (c < Cp && r < Rp) {
      float v = tile[tx][ty + i];
      if (MODE == 0) {
        out[(size_t)c * Rp + r] = f2bf(v);
      } else {
        __half h = __float2half(v);
        out[(size_t)c * Rp + r] = *(ushort_t*)&h;
      }
    }
  }
}

// ---------------- fuse: x_b[m][kp] = bf16(xtmp[m][kp] + E[words[m]][kp]) (kp<300), else 0 ----
__global__ void k_xfuse(const float* __restrict__ xtmp, const float* __restrict__ E,
                        const int* __restrict__ words, ushort_t* __restrict__ xb) {
  int m = blockIdx.x;
  int kp = threadIdx.x;  // 320 threads
  int w = words[m];
  float v = 0.f;
  if (kp < E_DIM) v = xtmp[(size_t)m * 320 + kp] + E[(size_t)w * E_DIM + kp];
  xb[(size_t)m * 320 + kp] = f2bf(v);
}

// ---------------- bf16 MFMA GEMM: C[m][n] = sum_k A[m][k]*BT[n][k] + bias[n] ----------------
// A: [M][K] bf16 row-major. BT: [Npad][K] bf16 row-major (pre-transposed B).
// 128x128 tile per block, 4 waves (2x2 of 64x64), BK=64, XOR-swizzled LDS.
__global__ __launch_bounds__(256, 2) void k_gemm_bt(
    const ushort_t* __restrict__ A, const ushort_t* __restrict__ BT,
    const float* __restrict__ bias, float* __restrict__ C,
    int M, int K, int Nreal, int ldc) {
  __shared__ __align__(16) char smem[32768];
  char* As = smem;            // [128 rows][8 slots of 16B], slot = c16 ^ (row&7)
  char* Bs = smem + 16384;
  const int tid = threadIdx.x;
  const int lane = tid & 63;
  const int w = tid >> 6;
  const int wr = w >> 1, wc = w & 1;
  const int m0 = blockIdx.x * 128;   // m-tile fastest-varying: same-B-panel blocks adjacent
  const int n0 = blockIdx.y * 128;

  f32x4 acc[4][4];
#pragma unroll
  for (int i = 0; i < 4; ++i)
#pragma unroll
    for (int j = 0; j < 4; ++j) acc[i][j] = (f32x4){0.f, 0.f, 0.f, 0.f};

  const int srow = tid >> 3;   // 0..31
  const int sc16 = tid & 7;    // 0..7

  for (int k0 = 0; k0 < K; k0 += 64) {
    __syncthreads();
#pragma unroll
    for (int it = 0; it < 4; ++it) {
      int row = srow + it * 32;
      int slot = sc16 ^ (row & 7);
      bf16x8 va = *(const bf16x8*)(A + (size_t)(m0 + row) * K + k0 + sc16 * 8);
      *(bf16x8*)(As + row * 128 + (slot << 4)) = va;
      bf16x8 vb = *(const bf16x8*)(BT + (size_t)(n0 + row) * K + k0 + sc16 * 8);
      *(bf16x8*)(Bs + row * 128 + (slot << 4)) = vb;
    }
    __syncthreads();

    bf16x8 af[4][2], bfr[4][2];
#pragma unroll
    for (int mi = 0; mi < 4; ++mi) {
      int r = wr * 64 + mi * 16 + (lane & 15);
#pragma unroll
      for (int kk = 0; kk < 2; ++kk) {
        int c16 = kk * 4 + (lane >> 4);
        af[mi][kk] = *(const bf16x8*)(As + r * 128 + ((c16 ^ (r & 7)) << 4));
      }
    }
#pragma unroll
    for (int ni = 0; ni < 4; ++ni) {
      int r = wc * 64 + ni * 16 + (lane & 15);
#pragma unroll
      for (int kk = 0; kk < 2; ++kk) {
        int c16 = kk * 4 + (lane >> 4);
        bfr[ni][kk] = *(const bf16x8*)(Bs + r * 128 + ((c16 ^ (r & 7)) << 4));
      }
    }
#pragma unroll
    for (int mi = 0; mi < 4; ++mi)
#pragma unroll
      for (int ni = 0; ni < 4; ++ni)
#pragma unroll
        for (int kk = 0; kk < 2; ++kk)
          acc[mi][ni] = __builtin_amdgcn_mfma_f32_16x16x32_bf16(af[mi][kk], bfr[ni][kk],
                                                                acc[mi][ni], 0, 0, 0);
  }

  // epilogue: D row=(lane>>4)*4+reg, col=lane&15  [verified m89 layout]
  const int rbase = m0 + wr * 64 + (lane >> 4) * 4;
  const int cbase = n0 + wc * 64 + (lane & 15);
#pragma unroll
  for (int ni = 0; ni < 4; ++ni) {
    int n = cbase + ni * 16;
    if (n < Nreal) {
      float bn = bias[n];
#pragma unroll
      for (int mi = 0; mi < 4; ++mi) {
#pragma unroll
        for (int rg = 0; rg < 4; ++rg) {
          int mrow = rbase + mi * 16 + rg;
          C[(size_t)mrow * ldc + n] = acc[mi][ni][rg] + bn;
        }
      }
    }
  }
}

// ---------------- GRU: 512 threads, thread pair (half, j) splits U column j ----------------
// Thread (half, j) owns k in [half*128, half*128+128) of U columns {j, j+256, j+512}
// register-resident as f16 (192 VGPRs) -> fits the 256-reg budget of 2 waves/EU, no spill.
// Per step: 16 broadcast ds_read_b128 of h-half + 192 fdot2; half-1 writes 3 partials to
// LDS; half-0 combines + gates thread-locally; double-buffered h; 2 barriers/step.
__global__ __launch_bounds__(512, 2) void k_gru(
    const float* __restrict__ gx, const ushort_t* __restrict__ UT,
    const float* __restrict__ bu, const int* __restrict__ words,
    ushort_t* __restrict__ seqb) {
  const int b = blockIdx.x;
  const int tid = threadIdx.x;
  const int j = tid & 255;
  const int half = tid >> 8;
  const int kbase = half * 128;

  __shared__ __align__(16) _Float16 hbuf[2][H_SZ];
  __shared__ float partial[3][H_SZ];
  __shared__ int words_s[T_SZ];

  // register-resident U half-columns (f16): z, r, n  (64 h2v each = 192 VGPRs)
  h2v uz[64], ur[64], un[64];
  {
    const h2v* pz = (const h2v*)(UT + (size_t)j * H_SZ + kbase);
    const h2v* pr = (const h2v*)(UT + (size_t)(H_SZ + j) * H_SZ + kbase);
    const h2v* pn = (const h2v*)(UT + (size_t)(2 * H_SZ + j) * H_SZ + kbase);
#pragma unroll
    for (int k = 0; k < 64; ++k) uz[k] = pz[k];
#pragma unroll
    for (int k = 0; k < 64; ++k) ur[k] = pr[k];
#pragma unroll
    for (int k = 0; k < 64; ++k) un[k] = pn[k];
  }
  float buz = 0.f, bur = 0.f, bun = 0.f;
  if (half == 0) {
    buz = bu[j];
    bur = bu[H_SZ + j];
    bun = bu[2 * H_SZ + j];
  }

  if (tid < H_SZ) hbuf[0][tid] = (_Float16)0.f;
  if (tid < T_SZ) words_s[tid] = words[b * T_SZ + tid];
  __syncthreads();

  const float* gxp = gx + (size_t)b * T_SZ * 768;
  float gxz = 0.f, gxr = 0.f, gxn = 0.f;
  if (half == 0) {
    gxz = gxp[j];
    gxr = gxp[H_SZ + j];
    gxn = gxp[2 * H_SZ + j];
  }
  float h_old = 0.f;
  int p = 0;

  for (int t = 0; t < T_SZ; ++t) {
    // prefetch next step's gx under the dot-product phase (half 0 only)
    float gxz_n = 0.f, gxr_n = 0.f, gxn_n = 0.f;
    if (half == 0 && t + 1 < T_SZ) {
      const float* g1 = gxp + (size_t)(t + 1) * 768;
      gxz_n = g1[j];
      gxr_n = g1[H_SZ + j];
      gxn_n = g1[2 * H_SZ + j];
    }

    const float4* hb4 = (const float4*)(&hbuf[p][kbase]);
    float az0 = 0.f, az1 = 0.f, az2 = 0.f, az3 = 0.f;
    float ar0 = 0.f, ar1 = 0.f, ar2 = 0.f, ar3 = 0.f;
    float an0 = 0.f, an1 = 0.f, an2 = 0.f, an3 = 0.f;
#pragma unroll
    for (int k4 = 0; k4 < 16; ++k4) {
      float4 hv = hb4[k4];  // broadcast read: 8 h values (f16)
      const h2v* hp = (const h2v*)(&hv);
      az0 = __builtin_amdgcn_fdot2(uz[4 * k4 + 0], hp[0], az0, false);
      ar0 = __builtin_amdgcn_fdot2(ur[4 * k4 + 0], hp[0], ar0, false);
      an0 = __builtin_amdgcn_fdot2(un[4 * k4 + 0], hp[0], an0, false);
      az1 = __builtin_amdgcn_fdot2(uz[4 * k4 + 1], hp[1], az1, false);
      ar1 = __builtin_amdgcn_fdot2(ur[4 * k4 + 1], hp[1], ar1, false);
      an1 = __builtin_amdgcn_fdot2(un[4 * k4 + 1], hp[1], an1, false);
      az2 = __builtin_amdgcn_fdot2(uz[4 * k4 + 2], hp[2], az2, false);
      ar2 = __builtin_amdgcn_fdot2(ur[4 * k4 + 2], hp[2], ar2, false);
      an2 = __builtin_amdgcn_fdot2(un[4 * k4 + 2], hp[2], an2, false);
      az3 = __builtin_amdgcn_fdot2(uz[4 * k4 + 3], hp[3], az3, false);
      ar3 = __builtin_amdgcn_fdot2(ur[4 * k4 + 3], hp[3], ar3, false);
      an3 = __builtin_amdgcn_fdot2(un[4 * k4 + 3], hp[3], an3, false);
    }
    float hzp = (az0 + az1) + (az2 + az3);
    float hrp = (ar0 + ar1) + (ar2 + ar3);
    float hnp = (an0 + an1) + (an2 + an3);

    if (half == 1) {
      partial[0][j] = hzp;
      partial[1][j] = hrp;
      partial[2][j] = hnp;
    }
    __syncthreads();
    if (half == 0) {
      float hz = hzp + partial[0][j] + buz;
      float hr = hrp + partial[1][j] + bur;
      float hn = hnp + partial[2][j] + bun;
      float z = 1.f / (1.f + __expf(-(gxz + hz)));
      float r = 1.f / (1.f + __expf(-(gxr + hr)));
      float nv = 2.f / (1.f + __expf(-2.f * (gxn + r * hn))) - 1.f;  // tanh
      float hnew = (words_s[t] != 0) ? (z * h_old + (1.f - z) * nv) : h_old;
      h_old = hnew;
      seqb[((size_t)b * T_SZ + t) * H_SZ + j] = f2bf(hnew);
      hbuf[p ^ 1][j] = (_Float16)hnew;
    }
    __syncthreads();

    gxz = gxz_n;
    gxr = gxr_n;
    gxn = gxn_n;
    p ^= 1;
  }
}

// ---------------- launcher ----------------
extern "C" void kernel_launch(void* const* d_in, const int* in_sizes, int n_in,
                              void* d_out, int out_size, void* d_ws, size_t ws_size,
                              hipStream_t stream) {
  const int*   words = (const int*)d_in[0];    // [32,256]
  const float* midis = (const float*)d_in[1];  // [32,256,128]
  const float* E     = (const float*)d_in[2];  // [10000,300]
  const float* Wm    = (const float*)d_in[3];  // [128,300]
  const float* bm    = (const float*)d_in[4];  // [300]
  const float* Wx    = (const float*)d_in[5];  // [300,768]
  const float* bx    = (const float*)d_in[6];  // [768]
  const float* U     = (const float*)d_in[7];  // [256,768]
  const float* bu    = (const float*)d_in[8];  // [768]
  const float* Wo    = (const float*)d_in[9];  // [256,10000]
  const float* bo    = (const float*)d_in[10]; // [10000]
  float* out = (float*)d_out;

  const int MT = B_SZ * T_SZ;  // 8192
  size_t off = 0;
  auto alloc = [&](size_t bytes) -> void* {
    void* p = (char*)d_ws + off;
    off += (bytes + 255) & ~(size_t)255;
    return p;
  };
  ushort_t* mid_b = (ushort_t*)alloc((size_t)MT * 128 * 2);
  ushort_t* WmT   = (ushort_t*)alloc((size_t)384 * 128 * 2);
  float*    xtmp  = (float*)   alloc((size_t)MT * 320 * 4);
  ushort_t* x_b   = (ushort_t*)alloc((size_t)MT * 320 * 2);
  ushort_t* WxT   = (ushort_t*)alloc((size_t)768 * 320 * 2);
  float*    gx    = (float*)   alloc((size_t)MT * 768 * 4);
  ushort_t* UT    = (ushort_t*)alloc((size_t)768 * 256 * 2);
  ushort_t* seq_b = (ushort_t*)alloc((size_t)MT * 256 * 2);
  ushort_t* WoT   = (ushort_t*)alloc((size_t)10112 * 256 * 2);
  (void)ws_size;

  // prep: casts + transposes
  k_cast_bf16<<<(MT * 128 + 255) / 256, 256, 0, stream>>>(midis, mid_b, MT * 128);
  k_transpose_cast<0><<<dim3(12, 4),  dim3(32, 8), 0, stream>>>(Wm, WmT, 128, 300, 128, 384);
  k_transpose_cast<0><<<dim3(24, 10), dim3(32, 8), 0, stream>>>(Wx, WxT, 300, 768, 320, 768);
  k_transpose_cast<0><<<dim3(316, 8), dim3(32, 8), 0, stream>>>(Wo, WoT, 256, 10000, 256, 10112);
  k_transpose_cast<1><<<dim3(24, 8),  dim3(32, 8), 0, stream>>>(U, UT, 256, 768, 256, 768);

  // xtmp = midis @ Wm + bm   (M=8192, K=128, Npad=384, Nreal=300, ldc=320)
  k_gemm_bt<<<dim3(64, 3), 256, 0, stream>>>(mid_b, WmT, bm, xtmp, MT, 128, 300, 320);
  // x_b = bf16(xtmp + E[words]) with k-pad zeros
  k_xfuse<<<MT, 320, 0, stream>>>(xtmp, E, words, x_b);
  // gx = x @ Wx + bx   (K=320, N=768)
  k_gemm_bt<<<dim3(64, 6), 256, 0, stream>>>(x_b, WxT, bx, gx, MT, 320, 768, 768);
  // GRU -> seq_b (bf16), split-column register-resident-U version
  k_gru<<<B_SZ, 512, 0, stream>>>(gx, UT, bu, words, seq_b);
  // logits = seq @ Wo + bo   (K=256, Npad=10112, Nreal=10000)
  k_gemm_bt<<<dim3(64, 79), 256, 0, stream>>>(seq_b, WoT, bo, out, MT, 256, 10000, 10000);
}

// Round 6
// 492.423 us; speedup vs baseline: 1.3793x; 1.0019x over previous
//
#include <hip/hip_runtime.h>
#include <hip/hip_fp16.h>

typedef unsigned short ushort_t;
typedef short bf16x8 __attribute__((ext_vector_type(8)));
typedef float f32x4 __attribute__((ext_vector_type(4)));
typedef _Float16 h2v __attribute__((ext_vector_type(2)));

#define B_SZ 32
#define T_SZ 256
#define V_SZ 10000
#define E_DIM 300
#define M_DIM 128
#define H_SZ 256

__device__ __forceinline__ ushort_t f2bf(float f) {
  unsigned u = __float_as_uint(f);
  unsigned r = u + 0x7fffu + ((u >> 16) & 1u);
  return (ushort_t)(r >> 16);
}

// ---------------- elementwise cast f32 -> bf16 ----------------
__global__ void k_cast_bf16(const float* __restrict__ in, ushort_t* __restrict__ out, int n) {
  int i = blockIdx.x * blockDim.x + threadIdx.x;
  if (i < n) out[i] = f2bf(in[i]);
}

// ---------------- transpose + cast: out[c][r] = in[r][c], zero-padded ----------------
// MODE 0: bf16 output, MODE 1: f16 output. out dims [Cp][Rp].
template <int MODE>
__global__ void k_transpose_cast(const float* __restrict__ in, ushort_t* __restrict__ out,
                                 int R, int C, int Rp, int Cp) {
  __shared__ float tile[32][33];
  int c0 = blockIdx.x * 32, r0 = blockIdx.y * 32;
  int tx = threadIdx.x, ty = threadIdx.y;  // (32,8)
#pragma unroll
  for (int i = 0; i < 32; i += 8) {
    int r = r0 + ty + i, c = c0 + tx;
    tile[ty + i][tx] = (r < R && c < C) ? in[(size_t)r * C + c] : 0.f;
  }
  __syncthreads();
#pragma unroll
  for (int i = 0; i < 32; i += 8) {
    int c = c0 + ty + i, r = r0 + tx;
    if (c < Cp && r < Rp) {
      float v = tile[tx][ty + i];
      if (MODE == 0) {
        out[(size_t)c * Rp + r] = f2bf(v);
      } else {
        __half h = __float2half(v);
        out[(size_t)c * Rp + r] = *(ushort_t*)&h;
      }
    }
  }
}

// ---------------- fuse: x_b[m][kp] = bf16(xtmp[m][kp] + E[words[m]][kp]) (kp<300), else 0 ----
__global__ void k_xfuse(const float* __restrict__ xtmp, const float* __restrict__ E,
                        const int* __restrict__ words, ushort_t* __restrict__ xb) {
  int m = blockIdx.x;
  int kp = threadIdx.x;  // 320 threads
  int w = words[m];
  float v = 0.f;
  if (kp < E_DIM) v = xtmp[(size_t)m * 320 + kp] + E[(size_t)w * E_DIM + kp];
  xb[(size_t)m * 320 + kp] = f2bf(v);
}

// ---------------- bf16 MFMA GEMM: C[m][n] = sum_k A[m][k]*BT[n][k] + bias[n] ----------------
// A: [M][K] bf16 row-major. BT: [Npad][K] bf16 row-major (pre-transposed B).
// 128x128 tile per block, 4 waves (2x2 of 64x64), BK=64, XOR-swizzled LDS.
__global__ __launch_bounds__(256, 2) void k_gemm_bt(
    const ushort_t* __restrict__ A, const ushort_t* __restrict__ BT,
    const float* __restrict__ bias, float* __restrict__ C,
    int M, int K, int Nreal, int ldc) {
  __shared__ __align__(16) char smem[32768];
  char* As = smem;            // [128 rows][8 slots of 16B], slot = c16 ^ (row&7)
  char* Bs = smem + 16384;
  const int tid = threadIdx.x;
  const int lane = tid & 63;
  const int w = tid >> 6;
  const int wr = w >> 1, wc = w & 1;
  const int m0 = blockIdx.x * 128;   // m-tile fastest-varying: same-B-panel blocks adjacent
  const int n0 = blockIdx.y * 128;

  f32x4 acc[4][4];
#pragma unroll
  for (int i = 0; i < 4; ++i)
#pragma unroll
    for (int j = 0; j < 4; ++j) acc[i][j] = (f32x4){0.f, 0.f, 0.f, 0.f};

  const int srow = tid >> 3;   // 0..31
  const int sc16 = tid & 7;    // 0..7

  for (int k0 = 0; k0 < K; k0 += 64) {
    __syncthreads();
#pragma unroll
    for (int it = 0; it < 4; ++it) {
      int row = srow + it * 32;
      int slot = sc16 ^ (row & 7);
      bf16x8 va = *(const bf16x8*)(A + (size_t)(m0 + row) * K + k0 + sc16 * 8);
      *(bf16x8*)(As + row * 128 + (slot << 4)) = va;
      bf16x8 vb = *(const bf16x8*)(BT + (size_t)(n0 + row) * K + k0 + sc16 * 8);
      *(bf16x8*)(Bs + row * 128 + (slot << 4)) = vb;
    }
    __syncthreads();

    bf16x8 af[4][2], bfr[4][2];
#pragma unroll
    for (int mi = 0; mi < 4; ++mi) {
      int r = wr * 64 + mi * 16 + (lane & 15);
#pragma unroll
      for (int kk = 0; kk < 2; ++kk) {
        int c16 = kk * 4 + (lane >> 4);
        af[mi][kk] = *(const bf16x8*)(As + r * 128 + ((c16 ^ (r & 7)) << 4));
      }
    }
#pragma unroll
    for (int ni = 0; ni < 4; ++ni) {
      int r = wc * 64 + ni * 16 + (lane & 15);
#pragma unroll
      for (int kk = 0; kk < 2; ++kk) {
        int c16 = kk * 4 + (lane >> 4);
        bfr[ni][kk] = *(const bf16x8*)(Bs + r * 128 + ((c16 ^ (r & 7)) << 4));
      }
    }
#pragma unroll
    for (int mi = 0; mi < 4; ++mi)
#pragma unroll
      for (int ni = 0; ni < 4; ++ni)
#pragma unroll
        for (int kk = 0; kk < 2; ++kk)
          acc[mi][ni] = __builtin_amdgcn_mfma_f32_16x16x32_bf16(af[mi][kk], bfr[ni][kk],
                                                                acc[mi][ni], 0, 0, 0);
  }

  // epilogue: D row=(lane>>4)*4+reg, col=lane&15  [verified m89 layout]
  const int rbase = m0 + wr * 64 + (lane >> 4) * 4;
  const int cbase = n0 + wc * 64 + (lane & 15);
#pragma unroll
  for (int ni = 0; ni < 4; ++ni) {
    int n = cbase + ni * 16;
    if (n < Nreal) {
      float bn = bias[n];
#pragma unroll
      for (int mi = 0; mi < 4; ++mi) {
#pragma unroll
        for (int rg = 0; rg < 4; ++rg) {
          int mrow = rbase + mi * 16 + rg;
          C[(size_t)mrow * ldc + n] = acc[mi][ni][rg] + bn;
        }
      }
    }
  }
}

// ---------------- GRU: 512 threads, thread pair (half, j) splits U column j ----------------
// Thread (half, j) owns k in [half*128, half*128+128) of U columns {j, j+256, j+512}
// register-resident as f16 (192 VGPRs). amdgpu_waves_per_eu(2,2) pins occupancy to
// exactly 2 waves/EU -> 256-VGPR budget, removing the allocator's incentive to spill
// (launch_bounds min-waves alone let it shrink to 124 regs and AGPR-spill U — round 4).
// Per step: 16 broadcast ds_read_b128 of h-half + 192 fdot2; half-1 writes 3 partials to
// LDS; half-0 combines + gates thread-locally; double-buffered h; 2 barriers/step.
__global__ __launch_bounds__(512)
__attribute__((amdgpu_waves_per_eu(2, 2))) void k_gru(
    const float* __restrict__ gx, const ushort_t* __restrict__ UT,
    const float* __restrict__ bu, const int* __restrict__ words,
    ushort_t* __restrict__ seqb) {
  const int b = blockIdx.x;
  const int tid = threadIdx.x;
  const int j = tid & 255;
  const int half = tid >> 8;
  const int kbase = half * 128;

  __shared__ __align__(16) _Float16 hbuf[2][H_SZ];
  __shared__ float partial[3][H_SZ];
  __shared__ int words_s[T_SZ];

  // register-resident U half-columns (f16): z, r, n  (64 h2v each = 192 VGPRs)
  h2v uz[64], ur[64], un[64];
  {
    const h2v* pz = (const h2v*)(UT + (size_t)j * H_SZ + kbase);
    const h2v* pr = (const h2v*)(UT + (size_t)(H_SZ + j) * H_SZ + kbase);
    const h2v* pn = (const h2v*)(UT + (size_t)(2 * H_SZ + j) * H_SZ + kbase);
#pragma unroll
    for (int k = 0; k < 64; ++k) uz[k] = pz[k];
#pragma unroll
    for (int k = 0; k < 64; ++k) ur[k] = pr[k];
#pragma unroll
    for (int k = 0; k < 64; ++k) un[k] = pn[k];
  }
  float buz = 0.f, bur = 0.f, bun = 0.f;
  if (half == 0) {
    buz = bu[j];
    bur = bu[H_SZ + j];
    bun = bu[2 * H_SZ + j];
  }

  if (tid < H_SZ) hbuf[0][tid] = (_Float16)0.f;
  if (tid < T_SZ) words_s[tid] = words[b * T_SZ + tid];
  __syncthreads();

  const float* gxp = gx + (size_t)b * T_SZ * 768;
  float gxz = 0.f, gxr = 0.f, gxn = 0.f;
  if (half == 0) {
    gxz = gxp[j];
    gxr = gxp[H_SZ + j];
    gxn = gxp[2 * H_SZ + j];
  }
  float h_old = 0.f;
  int p = 0;

  for (int t = 0; t < T_SZ; ++t) {
    // prefetch next step's gx under the dot-product phase (half 0 only)
    float gxz_n = 0.f, gxr_n = 0.f, gxn_n = 0.f;
    if (half == 0 && t + 1 < T_SZ) {
      const float* g1 = gxp + (size_t)(t + 1) * 768;
      gxz_n = g1[j];
      gxr_n = g1[H_SZ + j];
      gxn_n = g1[2 * H_SZ + j];
    }

    const float4* hb4 = (const float4*)(&hbuf[p][kbase]);
    float az0 = 0.f, az1 = 0.f, az2 = 0.f, az3 = 0.f;
    float ar0 = 0.f, ar1 = 0.f, ar2 = 0.f, ar3 = 0.f;
    float an0 = 0.f, an1 = 0.f, an2 = 0.f, an3 = 0.f;
#pragma unroll
    for (int k4 = 0; k4 < 16; ++k4) {
      float4 hv = hb4[k4];  // broadcast read: 8 h values (f16)
      const h2v* hp = (const h2v*)(&hv);
      az0 = __builtin_amdgcn_fdot2(uz[4 * k4 + 0], hp[0], az0, false);
      ar0 = __builtin_amdgcn_fdot2(ur[4 * k4 + 0], hp[0], ar0, false);
      an0 = __builtin_amdgcn_fdot2(un[4 * k4 + 0], hp[0], an0, false);
      az1 = __builtin_amdgcn_fdot2(uz[4 * k4 + 1], hp[1], az1, false);
      ar1 = __builtin_amdgcn_fdot2(ur[4 * k4 + 1], hp[1], ar1, false);
      an1 = __builtin_amdgcn_fdot2(un[4 * k4 + 1], hp[1], an1, false);
      az2 = __builtin_amdgcn_fdot2(uz[4 * k4 + 2], hp[2], az2, false);
      ar2 = __builtin_amdgcn_fdot2(ur[4 * k4 + 2], hp[2], ar2, false);
      an2 = __builtin_amdgcn_fdot2(un[4 * k4 + 2], hp[2], an2, false);
      az3 = __builtin_amdgcn_fdot2(uz[4 * k4 + 3], hp[3], az3, false);
      ar3 = __builtin_amdgcn_fdot2(ur[4 * k4 + 3], hp[3], ar3, false);
      an3 = __builtin_amdgcn_fdot2(un[4 * k4 + 3], hp[3], an3, false);
    }
    float hzp = (az0 + az1) + (az2 + az3);
    float hrp = (ar0 + ar1) + (ar2 + ar3);
    float hnp = (an0 + an1) + (an2 + an3);

    if (half == 1) {
      partial[0][j] = hzp;
      partial[1][j] = hrp;
      partial[2][j] = hnp;
    }
    __syncthreads();
    if (half == 0) {
      float hz = hzp + partial[0][j] + buz;
      float hr = hrp + partial[1][j] + bur;
      float hn = hnp + partial[2][j] + bun;
      float z = 1.f / (1.f + __expf(-(gxz + hz)));
      float r = 1.f / (1.f + __expf(-(gxr + hr)));
      float nv = 2.f / (1.f + __expf(-2.f * (gxn + r * hn))) - 1.f;  // tanh
      float hnew = (words_s[t] != 0) ? (z * h_old + (1.f - z) * nv) : h_old;
      h_old = hnew;
      seqb[((size_t)b * T_SZ + t) * H_SZ + j] = f2bf(hnew);
      hbuf[p ^ 1][j] = (_Float16)hnew;
    }
    __syncthreads();

    gxz = gxz_n;
    gxr = gxr_n;
    gxn = gxn_n;
    p ^= 1;
  }
}

// ---------------- launcher ----------------
extern "C" void kernel_launch(void* const* d_in, const int* in_sizes, int n_in,
                              void* d_out, int out_size, void* d_ws, size_t ws_size,
                              hipStream_t stream) {
  const int*   words = (const int*)d_in[0];    // [32,256]
  const float* midis = (const float*)d_in[1];  // [32,256,128]
  const float* E     = (const float*)d_in[2];  // [10000,300]
  const float* Wm    = (const float*)d_in[3];  // [128,300]
  const float* bm    = (const float*)d_in[4];  // [300]
  const float* Wx    = (const float*)d_in[5];  // [300,768]
  const float* bx    = (const float*)d_in[6];  // [768]
  const float* U     = (const float*)d_in[7];  // [256,768]
  const float* bu    = (const float*)d_in[8];  // [768]
  const float* Wo    = (const float*)d_in[9];  // [256,10000]
  const float* bo    = (const float*)d_in[10]; // [10000]
  float* out = (float*)d_out;

  const int MT = B_SZ * T_SZ;  // 8192
  size_t off = 0;
  auto alloc = [&](size_t bytes) -> void* {
    void* p = (char*)d_ws + off;
    off += (bytes + 255) & ~(size_t)255;
    return p;
  };
  ushort_t* mid_b = (ushort_t*)alloc((size_t)MT * 128 * 2);
  ushort_t* WmT   = (ushort_t*)alloc((size_t)384 * 128 * 2);
  float*    xtmp  = (float*)   alloc((size_t)MT * 320 * 4);
  ushort_t* x_b   = (ushort_t*)alloc((size_t)MT * 320 * 2);
  ushort_t* WxT   = (ushort_t*)alloc((size_t)768 * 320 * 2);
  float*    gx    = (float*)   alloc((size_t)MT * 768 * 4);
  ushort_t* UT    = (ushort_t*)alloc((size_t)768 * 256 * 2);
  ushort_t* seq_b = (ushort_t*)alloc((size_t)MT * 256 * 2);
  ushort_t* WoT   = (ushort_t*)alloc((size_t)10112 * 256 * 2);
  (void)ws_size;

  // prep: casts + transposes
  k_cast_bf16<<<(MT * 128 + 255) / 256, 256, 0, stream>>>(midis, mid_b, MT * 128);
  k_transpose_cast<0><<<dim3(12, 4),  dim3(32, 8), 0, stream>>>(Wm, WmT, 128, 300, 128, 384);
  k_transpose_cast<0><<<dim3(24, 10), dim3(32, 8), 0, stream>>>(Wx, WxT, 300, 768, 320, 768);
  k_transpose_cast<0><<<dim3(316, 8), dim3(32, 8), 0, stream>>>(Wo, WoT, 256, 10000, 256, 10112);
  k_transpose_cast<1><<<dim3(24, 8),  dim3(32, 8), 0, stream>>>(U, UT, 256, 768, 256, 768);

  // xtmp = midis @ Wm + bm   (M=8192, K=128, Npad=384, Nreal=300, ldc=320)
  k_gemm_bt<<<dim3(64, 3), 256, 0, stream>>>(mid_b, WmT, bm, xtmp, MT, 128, 300, 320);
  // x_b = bf16(xtmp + E[words]) with k-pad zeros
  k_xfuse<<<MT, 320, 0, stream>>>(xtmp, E, words, x_b);
  // gx = x @ Wx + bx   (K=320, N=768)
  k_gemm_bt<<<dim3(64, 6), 256, 0, stream>>>(x_b, WxT, bx, gx, MT, 320, 768, 768);
  // GRU -> seq_b (bf16), split-column register-resident-U, occupancy-pinned
  k_gru<<<B_SZ, 512, 0, stream>>>(gx, UT, bu, words, seq_b);
  // logits = seq @ Wo + bo   (K=256, Npad=10112, Nreal=10000)
  k_gemm_bt<<<dim3(64, 79), 256, 0, stream>>>(seq_b, WoT, bo, out, MT, 256, 10000, 10000);
}